// Round 14
// baseline (19.434 us; speedup 1.0000x reference)
//
#include <hip/hip_runtime.h>

// DMLoss: B=1024, Np=Ng=128, T=10.
// Round 14: r10 scan/combine VERBATIM (5 failed attempts to improve it:
// r11/r12/r13 — restructures that grow live state lose ~1.5us). Only the
// block TAIL changes:
//  - wave-direct global partials: lane0 of each wave writes its 3 sums to
//    global SoA [3][8*B]. Deletes 2nd barrier + s_red LDS round-trip +
//    3-thread serial write.
//  - quarter-split epilogue: q0 lanes do part-1 interp/L1, q1 lanes do
//    part-2 gather/mask; butterfly bits 0-3 (quarters stay separate), then
//    lane0 pulls l_c/l_m from lane16 (2 shuffles).
//  - __launch_bounds__(512,8) pin (protective).
//  LESSONS kept: tables not recomputed in-loop (r6/r9); no cross-block
//  atomics (r3/r7); rcp once in staging; exact t/10.0f; strict-< +
//  ascending-order tie-break = jnp.argmin first-occurrence.

constexpr int NP = 128;
constexpr int NG = 128;

__device__ __forceinline__ int padi (int i) { return i + (i >> 5); }  // stride-33
__device__ __forceinline__ int padi2(int i) { return i + (i >> 4); }  // stride-17

__global__ __launch_bounds__(512, 8) void dm_main(
    const float* __restrict__ ini,   // [B, NP, 2]
    const float* __restrict__ pp,    // [B, NP, 2]
    const float* __restrict__ gt,    // [B, NG, 2]
    const float* __restrict__ mask,  // [B, NG]
    float* __restrict__ partial,     // SoA: [3][8*B] (per-wave partials)
    int nb)
{
    const int b    = blockIdx.x;
    const int tid  = threadIdx.x;
    const int lane = tid & 63;
    const int w    = tid >> 6;             // wave 0..7

    __shared__ float2 s_gt  [NG];          // epilogue gathers (unpadded)
    __shared__ float4 s_seg [NG + 4];      // padded(>>5): {pv.x, pv.y, e10x, e10y}
    __shared__ float  s_g   [NG + 4];      // padded(>>5): |e|^2 / 100
    __shared__ float4 s_ini2[64 + 4];      // padded(>>4): {p0.x,p0.y,p1.x,p1.y}
    __shared__ float2 s_pp  [NP];          // epilogue gathers (unpadded)

    const float2* gtb  = (const float2*)(gt  + (size_t)b * 256);
    const float4* ini4 = (const float4*)(ini + (size_t)b * 256);
    const float2* ppb  = (const float2*)(pp  + (size_t)b * 256);

    // Staging; rcp ONCE per segment here (r6/r9 lesson: never in-loop).
    if (tid < 128) {
        const float2 cv = gtb[tid];
        const float2 pv = gtb[(tid + 127) & 127];
        const float ex = cv.x - pv.x, ey = cv.y - pv.y;
        const float ee = fmaf(ex, ex, ey * ey);
        const float s10 = 10.0f * __builtin_amdgcn_rcpf(fmaxf(ee, 1e-30f));
        s_gt [tid]       = cv;
        s_seg[padi(tid)] = make_float4(pv.x, pv.y, ex * s10, ey * s10);
        s_g  [padi(tid)] = ee * 0.01f;
    } else if (tid < 192) {
        const int i = tid - 128;           // pred pair 0..63
        s_ini2[padi2(i)] = ini4[i];
    } else if (tid < 320) {
        s_pp[tid - 192] = ppb[tid - 192];
    }

    const int sub     = lane & 15;         // point/vertex within wave's 16
    const int quarter = lane >> 4;         // 0..3
    const int pnt     = (w << 4) | sub;    // 0..127
    float mval = 0.0f;
    if (quarter == 1) mval = mask[(size_t)b * NG + pnt];   // q1 does part-2 epi
    __syncthreads();                       // the ONLY barrier

    // Queries from the packed pair table (broadcast-ish one-time reads)
    const float4 qq = s_ini2[padi2(pnt >> 1)];
    const float2 q  = (pnt & 1) ? make_float2(qq.z, qq.w) : make_float2(qq.x, qq.y);
    const float2 gv = s_gt[pnt];

    // ---- Part 1 scan: segments [quarter*32, +32) for point pnt (r10 verbatim) ----
    float bd1 = 3.4e38f, bi1 = 0.0f;
    {
        const int s0 = quarter << 5;
        float basef = (float)(s0 * 10);
        #pragma unroll 8
        for (int k = 0; k < 32; ++k) {
            const float4 sg = s_seg[padi(s0 + k)];    // b128, banks per quarter {0,4,8,12}
            const float  g  = s_g  [padi(s0 + k)];    // b32,  banks {0,1,2,3}
            const float wx = q.x - sg.x, wy = q.y - sg.y;
            const float tf = fmaf(wy, sg.w, wx * sg.z);      // = 10*dot(w,e)/|e|^2
            float tc = rintf(tf);
            tc = __builtin_amdgcn_fmed3f(tc, 0.0f, 9.0f);
            const float ww = fmaf(wy, wy, wx * wx);
            const float t2 = fmaf(-2.0f, tf, tc);
            const float d  = fmaf(g * tc, t2, ww);    // == |w-(tc/10)e|^2 (model)
            const float cand = basef + tc;
            bi1 = (d < bd1) ? cand : bi1;             // strict <: first occurrence
            bd1 = fminf(d, bd1);
            basef += 10.0f;
        }
    }

    // ---- Part 2 scan: pred pairs [quarter*16, +16) for gt vertex pnt (r10 verbatim) ----
    float bd2 = 3.4e38f, bj2 = 0.0f;
    {
        const int p0 = quarter << 4;
        float jf = (float)(quarter << 5);
        #pragma unroll 8
        for (int k = 0; k < 16; ++k) {
            const float4 pv2 = s_ini2[padi2(p0 + k)]; // one b128 -> 2 evals
            {
                const float dx = gv.x - pv2.x, dy = gv.y - pv2.y;
                const float d  = fmaf(dy, dy, dx * dx);
                bj2 = (d < bd2) ? jf : bj2;
                bd2 = fminf(d, bd2);
            }
            jf += 1.0f;
            {
                const float dx = gv.x - pv2.z, dy = gv.y - pv2.w;
                const float d  = fmaf(dy, dy, dx * dx);
                bj2 = (d < bd2) ? jf : bj2;
                bd2 = fminf(d, bd2);
            }
            jf += 1.0f;
        }
    }

    // ---- In-wave combine over quarters (lane bits 4,5); tie -> lower index.
    #pragma unroll
    for (int st = 16; st <= 32; st <<= 1) {
        const float d1o = __shfl_xor(bd1, st);
        const float i1o = __shfl_xor(bi1, st);
        const bool  t1  = (d1o < bd1) || (d1o == bd1 && i1o < bi1);
        bi1 = t1 ? i1o : bi1;
        bd1 = t1 ? d1o : bd1;
        const float d2o = __shfl_xor(bd2, st);
        const float j2o = __shfl_xor(bj2, st);
        const bool  t2  = (d2o < bd2) || (d2o == bd2 && j2o < bj2);
        bj2 = t2 ? j2o : bj2;
        bd2 = t2 ? d2o : bd2;
    }

    // ---- Quarter-split epilogue: q0 -> part 1; q1 -> part 2 ----
    float l_a = 0.0f, l_c = 0.0f, l_m = 0.0f;
    if (quarter == 0) {
        const int idx = (int)bi1;
        const int n = idx / 10;                       // magic-mul
        const int t = idx - n * 10;
        const float step = (float)t / 10.0f;          // exact ref: arange(T)/T
        const float om   = 1.0f - step;
        const float2 c   = s_gt[n];
        const float2 prv = s_gt[(n + NG - 1) & (NG - 1)];
        const float nx = c.x * step + prv.x * om;
        const float ny = c.y * step + prv.y * om;
        const float2 mp = s_pp[pnt];
        l_a = fabsf(mp.x - nx) + fabsf(mp.y - ny);
    } else if (quarter == 1) {
        const float2 npt = s_pp[(int)bj2];
        l_c = mval * (fabsf(npt.x - gv.x) + fabsf(npt.y - gv.y));
        l_m = 2.0f * mval;
    }

    // Butterfly bits 0..3 (quarters stay separate): lane0 gets full l_a,
    // lane16 gets full l_c/l_m.
    #pragma unroll
    for (int st = 1; st <= 8; st <<= 1) {
        l_a += __shfl_xor(l_a, st);
        l_c += __shfl_xor(l_c, st);
        l_m += __shfl_xor(l_m, st);
    }
    l_c = __shfl(l_c, 16);   // pull q1's sums down to lane 0
    l_m = __shfl(l_m, 16);

    // Wave-direct global partials (no 2nd barrier, no LDS round-trip)
    if (lane == 0) {
        const int wid = b * 8 + w;
        const int n8  = nb * 8;
        partial[wid]                 = l_a;
        partial[(size_t)n8 + wid]    = l_c;
        partial[(size_t)2 * n8 + wid] = l_m;
    }
}

__global__ __launch_bounds__(256) void dm_final(
    const float* __restrict__ partial, int n8, double inv_count, float* __restrict__ out)
{
    const int tid = threadIdx.x;
    double a = 0.0, c = 0.0, d = 0.0;
    const int npairs = n8 >> 2;                       // float4s per stream
    for (int i = tid; i < npairs; i += 256) {
        const float4 va = ((const float4*)partial)[i];
        const float4 vc = ((const float4*)(partial + (size_t)n8))[i];
        const float4 vd = ((const float4*)(partial + (size_t)2 * n8))[i];
        a += (double)va.x + (double)va.y + (double)va.z + (double)va.w;
        c += (double)vc.x + (double)vc.y + (double)vc.z + (double)vc.w;
        d += (double)vd.x + (double)vd.y + (double)vd.z + (double)vd.w;
    }
    for (int off = 32; off > 0; off >>= 1) {
        a += __shfl_down(a, off);
        c += __shfl_down(c, off);
        d += __shfl_down(d, off);
    }
    __shared__ double s[12];
    const int wid = tid >> 6, lane = tid & 63;
    if (lane == 0) { s[wid * 3] = a; s[wid * 3 + 1] = c; s[wid * 3 + 2] = d; }
    __syncthreads();
    if (tid == 0) {
        const double at = s[0] + s[3] + s[6] + s[9];
        const double ct = s[1] + s[4] + s[7] + s[10];
        const double dt = s[2] + s[5] + s[8] + s[11];
        const double loss = ct / (dt + 1.0) + at * inv_count;
        out[0] = (float)(loss * 0.5);
    }
}

extern "C" void kernel_launch(void* const* d_in, const int* in_sizes, int n_in,
                              void* d_out, int out_size, void* d_ws, size_t ws_size,
                              hipStream_t stream) {
    const float* ini  = (const float*)d_in[0];
    const float* pp   = (const float*)d_in[1];
    const float* gt   = (const float*)d_in[2];
    const float* mask = (const float*)d_in[3];
    float* out = (float*)d_out;

    const int B = in_sizes[0] / (NP * 2);
    float* partial = (float*)d_ws;                    // 3 * 8B floats

    dm_main<<<B, 512, 0, stream>>>(ini, pp, gt, mask, partial, B);
    const double inv_count = 1.0 / ((double)B * NP * 2);
    dm_final<<<1, 256, 0, stream>>>(partial, B * 8, inv_count, out);
}

// Round 15
// 17.103 us; speedup vs baseline: 1.1363x; 1.1363x over previous
//
#include <hip/hip_runtime.h>

// DMLoss: B=1024, Np=Ng=128, T=10.
// Round 15: REPRODUCIBILITY RUN — byte-identical resubmit of round 10
// (best measured: 17.25us). Rounds 11-14 tested scan-throughput, occupancy,
// ILP-fusion, and block-tail restructures; all landed 18.4-19.4us. This run
// decides whether r10's 17.25 was real or favorable noise (launch-dominated
// workload, single cross-run samples, est. noise +/-1us).
//  - Part 1 score-form: table {pv.x,pv.y,e10x,e10y} with e10 = e*10/|e|^2 and
//    g = |e|^2/100. tf = dot(w,e10); d = |w|^2 + g*tc*(tc-2tf).
//  - Part 2 packed pairs: float4 {p0,p1}, stride-17 pad.
//  - Padded s_seg (stride-33), in-wave quarter combine via shfl_xor with
//    index tie-break, SoA partials, two-kernel finish (cross-block atomics
//    cost ~40us: r3/r7). rcp once in staging (r6/r9). Exact t/10.0f.

constexpr int NP = 128;
constexpr int NG = 128;

__device__ __forceinline__ int padi (int i) { return i + (i >> 5); }  // stride-33
__device__ __forceinline__ int padi2(int i) { return i + (i >> 4); }  // stride-17

__global__ __launch_bounds__(512) void dm_main(
    const float* __restrict__ ini,   // [B, NP, 2]
    const float* __restrict__ pp,    // [B, NP, 2]
    const float* __restrict__ gt,    // [B, NG, 2]
    const float* __restrict__ mask,  // [B, NG]
    float* __restrict__ partial,     // SoA: [3][B]
    int nb)
{
    const int b    = blockIdx.x;
    const int tid  = threadIdx.x;
    const int lane = tid & 63;
    const int w    = tid >> 6;             // wave 0..7

    __shared__ float2 s_gt  [NG];          // epilogue gathers (unpadded)
    __shared__ float4 s_seg [NG + 4];      // padded(>>5): {pv.x, pv.y, e10x, e10y}
    __shared__ float  s_g   [NG + 4];      // padded(>>5): |e|^2 / 100
    __shared__ float4 s_ini2[64 + 4];      // padded(>>4): {p0.x,p0.y,p1.x,p1.y}
    __shared__ float2 s_pp  [NP];          // epilogue gathers (unpadded)
    __shared__ float  s_red [24];

    const float2* gtb  = (const float2*)(gt  + (size_t)b * 256);
    const float4* ini4 = (const float4*)(ini + (size_t)b * 256);
    const float2* ppb  = (const float2*)(pp  + (size_t)b * 256);

    // Staging (global loads only before the barrier); rcp ONCE per segment here.
    if (tid < 128) {
        const float2 cv = gtb[tid];
        const float2 pv = gtb[(tid + 127) & 127];
        const float ex = cv.x - pv.x, ey = cv.y - pv.y;
        const float ee = fmaf(ex, ex, ey * ey);
        const float s10 = 10.0f * __builtin_amdgcn_rcpf(fmaxf(ee, 1e-30f));
        s_gt [tid]       = cv;
        s_seg[padi(tid)] = make_float4(pv.x, pv.y, ex * s10, ey * s10);
        s_g  [padi(tid)] = ee * 0.01f;
    } else if (tid < 192) {
        const int i = tid - 128;           // pred pair 0..63
        s_ini2[padi2(i)] = ini4[i];
    } else if (tid < 320) {
        s_pp[tid - 192] = ppb[tid - 192];
    }

    const int sub     = lane & 15;         // point/vertex within wave's 16
    const int quarter = lane >> 4;         // 0..3
    const int pnt     = (w << 4) | sub;    // 0..127
    float mval = 0.0f;
    if (quarter == 0) mval = mask[(size_t)b * NG + pnt];
    __syncthreads();

    // Queries from the packed pair table (8 distinct addrs/wave, broadcast)
    const float4 qq = s_ini2[padi2(pnt >> 1)];
    const float2 q  = (pnt & 1) ? make_float2(qq.z, qq.w) : make_float2(qq.x, qq.y);
    const float2 gv = s_gt[pnt];

    // ---- Part 1 scan: segments [quarter*32, +32) for point pnt ----
    float bd1 = 3.4e38f, bi1 = 0.0f;
    {
        const int s0 = quarter << 5;
        float basef = (float)(s0 * 10);
        #pragma unroll 8
        for (int k = 0; k < 32; ++k) {
            const float4 sg = s_seg[padi(s0 + k)];    // b128, banks per quarter {0,4,8,12}
            const float  g  = s_g  [padi(s0 + k)];    // b32,  banks {0,1,2,3}
            const float wx = q.x - sg.x, wy = q.y - sg.y;
            const float tf = fmaf(wy, sg.w, wx * sg.z);      // = 10*dot(w,e)/|e|^2
            float tc = rintf(tf);
            tc = __builtin_amdgcn_fmed3f(tc, 0.0f, 9.0f);
            const float ww = fmaf(wy, wy, wx * wx);
            const float t2 = fmaf(-2.0f, tf, tc);
            const float d  = fmaf(g * tc, t2, ww);    // == |w-(tc/10)e|^2 (model)
            const float cand = basef + tc;
            bi1 = (d < bd1) ? cand : bi1;             // strict <: first occurrence
            bd1 = fminf(d, bd1);
            basef += 10.0f;
        }
    }

    // ---- Part 2 scan: pred pairs [quarter*16, +16) for gt vertex pnt ----
    float bd2 = 3.4e38f, bj2 = 0.0f;
    {
        const int p0 = quarter << 4;
        float jf = (float)(quarter << 5);
        #pragma unroll 8
        for (int k = 0; k < 16; ++k) {
            const float4 pv2 = s_ini2[padi2(p0 + k)]; // one b128 -> 2 evals
            {
                const float dx = gv.x - pv2.x, dy = gv.y - pv2.y;
                const float d  = fmaf(dy, dy, dx * dx);
                bj2 = (d < bd2) ? jf : bj2;
                bd2 = fminf(d, bd2);
            }
            jf += 1.0f;
            {
                const float dx = gv.x - pv2.z, dy = gv.y - pv2.w;
                const float d  = fmaf(dy, dy, dx * dx);
                bj2 = (d < bd2) ? jf : bj2;
                bd2 = fminf(d, bd2);
            }
            jf += 1.0f;
        }
    }

    // ---- In-wave combine over quarters (lane bits 4,5); tie -> lower index.
    #pragma unroll
    for (int st = 16; st <= 32; st <<= 1) {
        const float d1o = __shfl_xor(bd1, st);
        const float i1o = __shfl_xor(bi1, st);
        const bool  t1  = (d1o < bd1) || (d1o == bd1 && i1o < bi1);
        bi1 = t1 ? i1o : bi1;
        bd1 = t1 ? d1o : bd1;
        const float d2o = __shfl_xor(bd2, st);
        const float j2o = __shfl_xor(bj2, st);
        const bool  t2  = (d2o < bd2) || (d2o == bd2 && j2o < bj2);
        bj2 = t2 ? j2o : bj2;
        bd2 = t2 ? d2o : bd2;
    }

    // ---- Epilogue on quarter-0 lanes ----
    float l_a = 0.0f, l_c = 0.0f, l_m = 0.0f;
    if (quarter == 0) {
        const int idx = (int)bi1;
        const int n = idx / 10;                       // magic-mul
        const int t = idx - n * 10;
        const float step = (float)t / 10.0f;          // exact ref: arange(T)/T
        const float om   = 1.0f - step;
        const float2 c   = s_gt[n];
        const float2 prv = s_gt[(n + NG - 1) & (NG - 1)];
        const float nx = c.x * step + prv.x * om;
        const float ny = c.y * step + prv.y * om;
        const float2 mp = s_pp[pnt];
        l_a = fabsf(mp.x - nx) + fabsf(mp.y - ny);

        const float2 npt = s_pp[(int)bj2];
        l_c = mval * (fabsf(npt.x - gv.x) + fabsf(npt.y - gv.y));
        l_m = 2.0f * mval;
    }

    // Reduce the 16 quarter-0 lanes (others carry zeros)
    #pragma unroll
    for (int st = 1; st <= 8; st <<= 1) {
        l_a += __shfl_xor(l_a, st);
        l_c += __shfl_xor(l_c, st);
        l_m += __shfl_xor(l_m, st);
    }
    if (lane == 0) {
        s_red[w * 3 + 0] = l_a;
        s_red[w * 3 + 1] = l_c;
        s_red[w * 3 + 2] = l_m;
    }
    __syncthreads();
    if (tid < 3) {
        float s = 0.0f;
        #pragma unroll
        for (int ww = 0; ww < 8; ++ww) s += s_red[ww * 3 + tid];
        partial[(size_t)tid * nb + b] = s;            // SoA -> coalesced final
    }
}

__global__ __launch_bounds__(256) void dm_final(
    const float* __restrict__ partial, int nb, double inv_count, float* __restrict__ out)
{
    const int tid = threadIdx.x;
    double a = 0.0, c = 0.0, d = 0.0;
    if ((nb & 3) == 0) {
        const int npairs = nb >> 2;                   // float4s per stream
        for (int i = tid; i < npairs; i += 256) {
            const float4 va = ((const float4*)partial)[i];
            const float4 vc = ((const float4*)(partial + (size_t)nb))[i];
            const float4 vd = ((const float4*)(partial + (size_t)2 * nb))[i];
            a += (double)va.x + (double)va.y + (double)va.z + (double)va.w;
            c += (double)vc.x + (double)vc.y + (double)vc.z + (double)vc.w;
            d += (double)vd.x + (double)vd.y + (double)vd.z + (double)vd.w;
        }
    } else {
        for (int i = tid; i < nb; i += 256) {
            a += (double)partial[i];
            c += (double)partial[(size_t)nb + i];
            d += (double)partial[(size_t)2 * nb + i];
        }
    }
    for (int off = 32; off > 0; off >>= 1) {
        a += __shfl_down(a, off);
        c += __shfl_down(c, off);
        d += __shfl_down(d, off);
    }
    __shared__ double s[12];
    const int wid = tid >> 6, lane = tid & 63;
    if (lane == 0) { s[wid * 3] = a; s[wid * 3 + 1] = c; s[wid * 3 + 2] = d; }
    __syncthreads();
    if (tid == 0) {
        const double at = s[0] + s[3] + s[6] + s[9];
        const double ct = s[1] + s[4] + s[7] + s[10];
        const double dt = s[2] + s[5] + s[8] + s[11];
        const double loss = ct / (dt + 1.0) + at * inv_count;
        out[0] = (float)(loss * 0.5);
    }
}

extern "C" void kernel_launch(void* const* d_in, const int* in_sizes, int n_in,
                              void* d_out, int out_size, void* d_ws, size_t ws_size,
                              hipStream_t stream) {
    const float* ini  = (const float*)d_in[0];
    const float* pp   = (const float*)d_in[1];
    const float* gt   = (const float*)d_in[2];
    const float* mask = (const float*)d_in[3];
    float* out = (float*)d_out;

    const int B = in_sizes[0] / (NP * 2);
    float* partial = (float*)d_ws;                    // 3*B floats

    dm_main<<<B, 512, 0, stream>>>(ini, pp, gt, mask, partial, B);
    const double inv_count = 1.0 / ((double)B * NP * 2);
    dm_final<<<1, 256, 0, stream>>>(partial, B, inv_count, out);
}